// Round 7
// baseline (174.819 us; speedup 1.0000x reference)
//
#include <hip/hip_runtime.h>

typedef short bh8 __attribute__((ext_vector_type(8)));          // 8 bf16 (4 VGPR) MFMA frag
typedef float f32x16 __attribute__((ext_vector_type(16)));      // MFMA C/D
typedef float f32x4 __attribute__((ext_vector_type(4), aligned(4)));

constexpr int S = 256, NL = 17, L = 19, ST = 17, EN = 18;

__device__ __forceinline__ short bft(float x) { return (short)(__float_as_uint(x) >> 16); }
__device__ __forceinline__ constexpr int rowOf(int j, int h) { return (j & 3) + 8 * (j >> 2) + 4 * h; }

// One block = 32 sequences. Wave 0: fwd y' = E(el o y), y1 = E[:,start], MFMA
// steps s=0..nf-1 (token s), snapshot (el_nf o y) at s==nf.  Wave 1: bwd
// w' = E^T(el o w), w_len = E[end,:], steps s=0..nb-1 (token len-1-s),
// snapshot w at s==nb.  nf=(len-1)>>1, nb=len>>1.  norm = m_f+m_b+log(sum w*(el o y)).
// MFMA v_mfma_f32_32x32x16_bf16: m=dest state, n=sequence, K=source state with
// permutation phi chosen so D regs ARE the next B regs (zero cross-lane/LDS in loop):
//   A[m=lane&31][k=(lane>>5)*8+j], B[k=(lane>>5)*8+j][n=lane&31],
//   D: col=lane&31, row=(reg&3)+8*(reg>>2)+4*(lane>>5)  [verified layout]
//   state(k): k=8h+j -> rowOf(j,h); k=16+8h+j -> rowOf(j+8,h). Only state 16 of
//   the second MFMA is real (17=start,18=end have el=0; >=19 padded zero).
__global__ __launch_bounds__(128)
void crf_mfma(const float* __restrict__ logits, const int* __restrict__ labels,
              const int* __restrict__ lens, const float* __restrict__ transition,
              float* __restrict__ out)
{
    __shared__ float Tsh[L * L];
    __shared__ float fbuf[32][21];   // fwd snapshot (el o y), rows 0..16; pad 21
    __shared__ float mfbuf[32];      // fwd log-scale m_f
    __shared__ float nrmbuf[32];
    __shared__ float gbuf[4][32];

    const int tid  = threadIdx.x;
    const int wv   = tid >> 6;       // 0 = fwd, 1 = bwd
    const int lane = tid & 63;
    const int h    = lane >> 5;
    const int n    = lane & 31;      // sequence within group; also A-row m
    const int b    = blockIdx.x * 32 + n;

    for (int k = tid; k < L * L; k += 128) Tsh[k] = transition[k];
    __syncthreads();

    // ---- constant A fragments (exp(T), permuted K, bf16) ----
    bh8 A0, A1;
    #pragma unroll
    for (int j = 0; j < 8; ++j) {
        const int st = rowOf(j, h);              // state of K-index 8h+j (<=15)
        float a = 0.f;
        if (n < 17) a = wv ? __expf(Tsh[st * L + n]) : __expf(Tsh[n * L + st]);
        A0[j] = bft(a);
        float a1 = 0.f;                          // K-index 16 = state 16 (h0,j0 only)
        if (j == 0 && h == 0 && n < 17)
            a1 = wv ? __expf(Tsh[16 * L + n]) : __expf(Tsh[n * L + 16]);
        A1[j] = bft(a1);
    }

    // ---- init state vector in D layout ----
    f32x16 D, zacc;
    #pragma unroll
    for (int j = 0; j < 16; ++j) {
        const int r = rowOf(j, h);
        float v = 0.f;
        if (r < 17) v = wv ? __expf(Tsh[EN * L + r])    // w_len = E[end,:]
                           : __expf(Tsh[r * L + ST]);   // y_1  = E[:,start]
        D[j] = v;
        zacc[j] = 0.f;
    }

    const int len = lens[b];
    const int nf = (len - 1) >> 1, nb = len >> 1;
    const int nup = wv ? nb : nf;                // this lane's snapshot step
    int red = nup;
    #pragma unroll
    for (int o = 32; o >= 1; o >>= 1) red = max(red, __shfl_xor(red, o));
    const int myN = red + 1;                     // loop covers s == nup for all lanes

    // ---- depth-4 prefetch of el inputs (per-lane 2x float4 + 1 float) ----
    const char* base = (const char*)logits + (size_t)b * (S * NL * 4);
    const char* p0 = base + 16 * h;              // states 4h..4h+3
    const char* p1 = base + 32 + 16 * h;         // states 8+4h..11+4h
    const char* p2 = base + 64;                  // state 16
    #define TOK(s_) ({ int t_ = wv ? (len - 1 - (s_)) : (s_); \
                       t_ = t_ < 0 ? 0 : (t_ > 255 ? 255 : t_); t_ * 68; })
    f32x4 q0[4], q1[4]; float qe[4];
    #pragma unroll
    for (int u = 0; u < 4; ++u) {
        const int t = TOK(u);
        q0[u] = *(const f32x4*)(p0 + t); q1[u] = *(const f32x4*)(p1 + t);
        qe[u] = *(const float*)(p2 + t);
    }

    float m = 0.f, mx = 1.f;
    float ws[9];
    #pragma unroll
    for (int j = 0; j < 9; ++j) ws[j] = 0.f;

    const int loop4 = (myN + 3) & ~3;
    for (int tb = 0; tb < loop4; tb += 4) {
        #pragma unroll
        for (int u = 0; u < 4; ++u) {
            const int s = tb + u;
            const f32x4 c0 = q0[u], c1 = q1[u]; const float ce = qe[u];
            { const int t = TOK(s + 4);
              q0[u] = *(const f32x4*)(p0 + t); q1[u] = *(const f32x4*)(p1 + t);
              qe[u] = *(const float*)(p2 + t); }

            if (wv) {                            // bwd: latch w at s == nb (pre-update)
                const bool snap = (s == nup);
                #pragma unroll
                for (int j = 0; j < 9; ++j) ws[j] = snap ? D[j] : ws[j];
            }

            float raw[8], raw8;
            raw[0] = __expf(c0[0]) * D[0];  raw[1] = __expf(c0[1]) * D[1];
            raw[2] = __expf(c0[2]) * D[2];  raw[3] = __expf(c0[3]) * D[3];
            raw[4] = __expf(c1[0]) * D[4];  raw[5] = __expf(c1[1]) * D[5];
            raw[6] = __expf(c1[2]) * D[6];  raw[7] = __expf(c1[3]) * D[7];
            raw8   = __expf(ce)    * D[8];   // state 16 (h0 meaningful)

            if (!wv && s == nup) {               // fwd: snapshot el_nf o y_(nf+1)
                #pragma unroll
                for (int j = 0; j < 8; ++j) fbuf[n][rowOf(j, h)] = raw[j];
                if (h == 0) { fbuf[n][16] = raw8; mfbuf[n] = m; }
            }

            if ((s & 3) == 3) {                  // renorm (mx from s-1, off-chain)
                const float sc = __frcp_rn(mx);
                #pragma unroll
                for (int j = 0; j < 8; ++j) raw[j] *= sc;
                raw8 *= sc;
                m += (s < nup) ? __logf(mx) : 0.f;
            }

            bh8 B0, B1;
            #pragma unroll
            for (int j = 0; j < 8; ++j) { B0[j] = bft(raw[j]); B1[j] = 0; }
            if (h == 0) B1[0] = bft(raw8);

            D = __builtin_amdgcn_mfma_f32_32x32x16_bf16(A0, B0, zacc, 0, 0, 0);
            D = __builtin_amdgcn_mfma_f32_32x32x16_bf16(A1, B1, D, 0, 0, 0);

            if ((s & 3) == 2) {                  // per-seq max for next renorm
                float lm = D[0];
                #pragma unroll
                for (int j = 1; j < 16; ++j) lm = fmaxf(lm, D[j]);
                mx = fmaxf(lm, __shfl_xor(lm, 32));
            }
        }
    }

    __syncthreads();                             // fbuf/mfbuf visible to bwd wave

    if (wv) {                                    // P = sum_r w[r] * (el o y)[r]
        float part = 0.f;
        #pragma unroll
        for (int j = 0; j < 8; ++j) part += ws[j] * fbuf[n][rowOf(j, h)];
        if (h == 0) part += ws[8] * fbuf[n][16];
        part += __shfl_xor(part, 32);
        if (h == 0) nrmbuf[n] = mfbuf[n] + m + __logf(part);
    }

    // ---- gold path score: 4 threads per sequence ----
    {
        const int jj = tid >> 5;                 // 0..3
        const int* labp = labels + b * S;
        const float* lgp = (const float*)base;
        float g = 0.f;
        for (int t = jj; t < len; t += 4) {
            const int lab = labp[t];
            const int prv = t ? labp[t - 1] : ST;
            g += lgp[t * NL + lab] + Tsh[lab * L + prv];
            if (t == len - 1) g += Tsh[EN * L + lab];
        }
        gbuf[jj][n] = g;
    }
    __syncthreads();
    if (tid < 32) {
        const float gold = gbuf[0][tid] + gbuf[1][tid] + gbuf[2][tid] + gbuf[3][tid];
        out[blockIdx.x * 32 + tid] = gold - nrmbuf[tid];
    }
}

extern "C" void kernel_launch(void* const* d_in, const int* in_sizes, int n_in,
                              void* d_out, int out_size, void* d_ws, size_t ws_size,
                              hipStream_t stream)
{
    (void)n_in; (void)out_size; (void)d_ws; (void)ws_size;
    const float* logits     = (const float*)d_in[0];
    const int*   labels     = (const int*)d_in[1];
    const int*   lens       = (const int*)d_in[2];
    const float* transition = (const float*)d_in[3];
    float*       out        = (float*)d_out;
    const int B = in_sizes[2];
    crf_mfma<<<dim3(B / 32), dim3(128), 0, stream>>>(logits, labels, lens, transition, out);
}

// Round 8
// 173.128 us; speedup vs baseline: 1.0098x; 1.0098x over previous
//
#include <hip/hip_runtime.h>

typedef short bh8 __attribute__((ext_vector_type(8)));
typedef float f32x16 __attribute__((ext_vector_type(16)));
typedef float f32x4 __attribute__((ext_vector_type(4)));

constexpr int S = 256, NL = 17, L = 19, ST = 17, EN = 18;
constexpr int ROWB = S * NL * 4;   // 17408 bytes per sequence
constexpr int RSTR = 76;           // staged LDS row stride in dwords (304 B)

__device__ __forceinline__ short bft(float x) { return (short)(__float_as_uint(x) >> 16); }
__device__ __forceinline__ constexpr int rowOf(int j, int h) { return (j & 3) + 8 * (j >> 2) + 4 * h; }

// One block = 32 sequences, 2 waves. Wave 0: fwd y' = E(el o y), y1 = E[:,start],
// snapshot raw = el_nf o y at s==nf. Wave 1: bwd w' = E^T(el o w), w_len = E[end,:],
// latch w at s==nb (pre-update). nf=(len-1)>>1, nb=len>>1, len-nb = nf+1.
// norm = m_f + m_b + log(sum_r w[r]*(el o y)[r]).  (math verified in R7)
// MFMA 32x32x16 bf16, m=dest state, n=seq; K-permutation phi(k=8h+j)=rowOf(j,h)
// makes D regs directly reusable as next-step B regs (zero cross-lane in loop).
// NEW: coalesced staging — 2 lanes/seq load the group's 272-288 contiguous bytes
// (16B-aligned chunks) into regs at group top, commit to LDS at group bottom
// (single buffer; per-wave DS in-order makes read-before-overwrite safe).
__global__ __launch_bounds__(128)
void crf_mfma(const float* __restrict__ logits, const int* __restrict__ labels,
              const int* __restrict__ lens, const float* __restrict__ transition,
              float* __restrict__ out, int capB)
{
    __shared__ float Tsh[L * L];
    __shared__ __align__(16) float stg[2][32 * RSTR];   // [wave][seq*RSTR]
    __shared__ float fbuf[32][21];
    __shared__ float mfbuf[32], nrm[32];
    __shared__ float gbuf[4][32];

    const int tid = threadIdx.x, wv = tid >> 6, lane = tid & 63;
    const int h = lane >> 5, n = lane & 31;
    const int b0 = blockIdx.x * 32;
    const int b  = b0 + n;

    for (int k = tid; k < L * L; k += 128) Tsh[k] = transition[k];
    __syncthreads();

    // ---- constant A fragments (exp(T), permuted K, bf16) ----
    bh8 A0, A1;
    #pragma unroll
    for (int j = 0; j < 8; ++j) {
        const int st = rowOf(j, h);
        float a = 0.f;
        if (n < 17) a = wv ? __expf(Tsh[st * L + n]) : __expf(Tsh[n * L + st]);
        A0[j] = bft(a);
        float a1 = 0.f;
        if (j == 0 && h == 0 && n < 17)
            a1 = wv ? __expf(Tsh[16 * L + n]) : __expf(Tsh[n * L + 16]);
        A1[j] = bft(a1);
    }

    // ---- init state vector in D layout ----
    f32x16 D, zacc;
    #pragma unroll
    for (int j = 0; j < 16; ++j) {
        const int r = rowOf(j, h);
        float v = 0.f;
        if (r < 17) v = wv ? __expf(Tsh[EN * L + r]) : __expf(Tsh[r * L + ST]);
        D[j] = v; zacc[j] = 0.f;
    }

    const int len  = lens[b];
    const int lenS = lens[b0 + (lane >> 1)];   // staging role: seq lane>>1
    const int nf = (len - 1) >> 1, nb = len >> 1;
    const int nup = wv ? nb : nf;
    int red = nup;
    #pragma unroll
    for (int o = 32; o >= 1; o >>= 1) red = max(red, __shfl_xor(red, o));
    const int nGroups = (red + 4) >> 2;

    const char* gptr = (const char*)logits;
    const int sn = lane >> 1, sp = lane & 1;
    const int srowG = (b0 + sn) * ROWB;

    float* srow = &stg[wv][0] + sn * RSTR;                  // staging write row
    const char* crow = (const char*)(&stg[wv][0] + n * RSTR); // compute read row

    // staged window base (bytes within seq row), 16B-aligned
    auto stage_abs = [&](int g) -> int {
        if (!wv) return 272 * g;
        int t3b = (lenS - 4 - 4 * g) * 68;
        t3b = t3b > 0 ? t3b : 0;
        return t3b & ~15;
    };

    f32x4 ld[9];
    // ---- prologue: stage group 0 ----
    {
        const int a0 = stage_abs(0);
        #pragma unroll
        for (int t = 0; t < 9; ++t) {
            int o = srowG + a0 + (sp + 2 * t) * 16;
            o = min(o, capB);
            ld[t] = *(const f32x4*)(gptr + o);
        }
        #pragma unroll
        for (int t = 0; t < 9; ++t)
            *(f32x4*)((char*)srow + (sp + 2 * t) * 16) = ld[t];
    }

    float m = 0.f, mx = 1.f, mf = 0.f;
    float fs[9], ws[9];
    #pragma unroll
    for (int j = 0; j < 9; ++j) { fs[j] = 0.f; ws[j] = 0.f; }

    for (int g = 0; g < nGroups; ++g) {
        // issue coalesced loads for group g+1 (commit at bottom)
        const int an = stage_abs(g + 1);
        #pragma unroll
        for (int t = 0; t < 9; ++t) {
            int o = srowG + an + (sp + 2 * t) * 16;
            o = min(o, capB);
            ld[t] = *(const f32x4*)(gptr + o);
        }

        // read-offset base for this group (own seq)
        int rbase = 0;
        if (wv) {
            int t3b = (len - 4 - 4 * g) * 68;
            int cb = t3b > 0 ? t3b : 0;
            rbase = (len - 1 - 4 * g) * 68 - (cb & ~15);
        }

        #pragma unroll
        for (int u = 0; u < 4; ++u) {
            const int s = 4 * g + u;
            const int rd = wv ? (rbase - 68 * u) : (68 * u);
            const float* cp = (const float*)(crow + rd + 16 * h);
            const float e0 = cp[0], e1 = cp[1], e2 = cp[2], e3 = cp[3];
            const float f0 = cp[8], f1 = cp[9], f2 = cp[10], f3 = cp[11];
            const float ee = *(const float*)(crow + rd + 64);

            if (wv) {                         // bwd: latch w at s==nb (pre-update)
                const bool snp = (s == nup);
                #pragma unroll
                for (int j = 0; j < 9; ++j) ws[j] = snp ? D[j] : ws[j];
            }

            float raw[9];
            raw[0] = __expf(e0) * D[0];  raw[1] = __expf(e1) * D[1];
            raw[2] = __expf(e2) * D[2];  raw[3] = __expf(e3) * D[3];
            raw[4] = __expf(f0) * D[4];  raw[5] = __expf(f1) * D[5];
            raw[6] = __expf(f2) * D[6];  raw[7] = __expf(f3) * D[7];
            raw[8] = __expf(ee) * D[8];  // state 16 (h0 meaningful; h1: D[8]=0)

            if (!wv) {                        // fwd: snapshot el_nf o y at s==nf
                const bool snp = (s == nup);
                #pragma unroll
                for (int j = 0; j < 9; ++j) fs[j] = snp ? raw[j] : fs[j];
                mf = snp ? m : mf;
            }

            if (u == 2) {                     // renorm scale from raw (off MFMA chain)
                float lm = fmaxf(fmaxf(fmaxf(raw[0], raw[1]), fmaxf(raw[2], raw[3])),
                                 fmaxf(fmaxf(raw[4], raw[5]), fmaxf(raw[6], raw[7])));
                lm = fmaxf(lm, raw[8]);
                mx = fmaxf(lm, __shfl_xor(lm, 32));
            }
            if (u == 3) {
                const float sc = __frcp_rn(mx);
                #pragma unroll
                for (int j = 0; j < 9; ++j) raw[j] *= sc;
                m += (s < nup) ? __logf(mx) : 0.f;
            }

            bh8 B0, B1;
            #pragma unroll
            for (int j = 0; j < 8; ++j) { B0[j] = bft(raw[j]); B1[j] = 0; }
            if (h == 0) B1[0] = bft(raw[8]);

            D = __builtin_amdgcn_mfma_f32_32x32x16_bf16(A0, B0, zacc, 0, 0, 0);
            D = __builtin_amdgcn_mfma_f32_32x32x16_bf16(A1, B1, D, 0, 0, 0);
        }

        // commit staged loads (single buffer: DS in-order per wave protects g reads)
        #pragma unroll
        for (int t = 0; t < 9; ++t)
            *(f32x4*)((char*)srow + (sp + 2 * t) * 16) = ld[t];
    }

    // ---- combine ----
    if (!wv) {
        #pragma unroll
        for (int j = 0; j < 8; ++j) fbuf[n][rowOf(j, h)] = fs[j];
        if (h == 0) { fbuf[n][16] = fs[8]; mfbuf[n] = mf; }
    }
    __syncthreads();
    if (wv) {
        float part = 0.f;
        #pragma unroll
        for (int j = 0; j < 8; ++j) part += ws[j] * fbuf[n][rowOf(j, h)];
        if (h == 0) part += ws[8] * fbuf[n][16];
        part += __shfl_xor(part, 32);
        if (h == 0) nrm[n] = mfbuf[n] + m + __logf(part);
    }

    // ---- gold path score: 4 threads per sequence ----
    {
        const int jj = tid >> 5;
        const int* labp = labels + b * S;
        const float* lgp = (const float*)(gptr + (size_t)b * ROWB);
        float g2 = 0.f;
        for (int t = jj; t < len; t += 4) {
            const int lab = labp[t];
            const int prv = t ? labp[t - 1] : ST;
            g2 += lgp[t * NL + lab] + Tsh[lab * L + prv];
            if (t == len - 1) g2 += Tsh[EN * L + lab];
        }
        gbuf[jj][n] = g2;
    }
    __syncthreads();
    if (tid < 32) {
        const float gold = gbuf[0][tid] + gbuf[1][tid] + gbuf[2][tid] + gbuf[3][tid];
        out[b0 + tid] = gold - nrm[tid];
    }
}

extern "C" void kernel_launch(void* const* d_in, const int* in_sizes, int n_in,
                              void* d_out, int out_size, void* d_ws, size_t ws_size,
                              hipStream_t stream)
{
    (void)n_in; (void)out_size; (void)d_ws; (void)ws_size;
    const float* logits     = (const float*)d_in[0];
    const int*   labels     = (const int*)d_in[1];
    const int*   lens       = (const int*)d_in[2];
    const float* transition = (const float*)d_in[3];
    float*       out        = (float*)d_out;
    const int B = in_sizes[2];
    const int capB = B * S * NL * 4 - 16;
    crf_mfma<<<dim3(B / 32), dim3(128), 0, stream>>>(logits, labels, lens, transition, out, capB);
}